// Round 1
// baseline (178.026 us; speedup 1.0000x reference)
//
#include <hip/hip_runtime.h>
#include <hip/hip_bf16.h>
#include <math.h>

// Problem constants (from reference)
#define INPUT_DIM 30000
#define UNITS     2048
#define NNZ       500000
#define BATCH     32

// ---------------------------------------------------------------------------
// Kernel 1: transpose x [32][30000] -> xt [30000][32]
// Coalesced writes; reads are strided but fully L1/L2-reused (each 64B line of
// x serves 16 consecutive i for one b). Total traffic ~8 MB -> ~1-2 us.
// ---------------------------------------------------------------------------
__global__ __launch_bounds__(256) void transpose_k(const float* __restrict__ x,
                                                   float* __restrict__ xt) {
    int tid = blockIdx.x * 256 + threadIdx.x;     // 0 .. 960000-1
    int i = tid >> 5;                             // input-dim index
    int b = tid & 31;                             // batch index
    xt[tid] = x[b * INPUT_DIM + i];
}

// ---------------------------------------------------------------------------
// Kernel 2: scatter-accumulate.
// grid = (nchunk, 4): blockIdx.x = nnz chunk, blockIdx.y = batch group (8 rows).
// LDS acc covers ALL 2048 columns x 8 batch rows = 64 KB  -> no filtering,
// no divergence, no global atomics. Each entry is handled by 8 lanes (one per
// batch row in the group). LDS bank: (c*8+b)&31 -> conflict-free per octet.
// Each WG writes its exclusive partial slab [2048*8] to workspace.
// ---------------------------------------------------------------------------
__global__ __launch_bounds__(1024) void scatter_k(const int* __restrict__ idx,
                                                  const float* __restrict__ kv,
                                                  const float* __restrict__ xt,
                                                  float* __restrict__ part,
                                                  int nchunk) {
    __shared__ float acc[UNITS * 8];              // 64 KB

    const int chunk = blockIdx.x;
    const int bg    = blockIdx.y;                 // batch group 0..3

    for (int t = threadIdx.x; t < UNITS * 8; t += 1024) acc[t] = 0.0f;
    __syncthreads();

    // int64 vs int32 index detection (uniform): for int64 little-endian COO
    // pairs the odd 32-bit words of entries 1..3 are zero; for int32 they are
    // cols 281/562/843 (nonzero).
    const bool is64 = ((idx[3] | idx[5] | idx[7]) == 0);

    const long long e0 = (long long)NNZ * chunk / nchunk;
    const long long e1 = (long long)NNZ * (chunk + 1) / nchunk;

    const int bl = threadIdx.x & 7;               // batch-local 0..7
    const int b  = bg * 8 + bl;                   // global batch row
    const int eo = threadIdx.x >> 3;              // entry offset 0..127

    if (is64) {
        const int4* __restrict__ p = (const int4*)idx;   // {row_lo,row_hi,col_lo,col_hi}
        for (long long e = e0 + eo; e < e1; e += 128) {
            int4 q  = p[e];
            float v = kv[e];
            atomicAdd(&acc[q.z * 8 + bl], v * xt[q.x * 32 + b]);
        }
    } else {
        const int2* __restrict__ p = (const int2*)idx;   // {row, col}
        for (long long e = e0 + eo; e < e1; e += 128) {
            int2 q  = p[e];
            float v = kv[e];
            atomicAdd(&acc[q.y * 8 + bl], v * xt[q.x * 32 + b]);
        }
    }
    __syncthreads();

    float* __restrict__ dst = part + (size_t)(bg * nchunk + chunk) * (UNITS * 8);
    for (int t = threadIdx.x; t < UNITS * 8; t += 1024) dst[t] = acc[t];
}

// ---------------------------------------------------------------------------
// Kernel 3: reduce partials over chunks, add bias, tanh, write out [32][2048].
// ---------------------------------------------------------------------------
__global__ __launch_bounds__(256) void reduce_k(const float* __restrict__ part,
                                                const float* __restrict__ bias,
                                                float* __restrict__ out,
                                                int nchunk) {
    int o = blockIdx.x * 256 + threadIdx.x;       // 0 .. 65535
    int b = o >> 11;                              // batch row
    int c = o & 2047;                             // unit/column
    int bg = b >> 3;
    int bl = b & 7;
    const float* __restrict__ p =
        part + (size_t)bg * nchunk * (UNITS * 8) + c * 8 + bl;
    float s = 0.0f;
    for (int k = 0; k < nchunk; ++k) s += p[(size_t)k * (UNITS * 8)];
    out[o] = tanhf(s + bias[c]);
}

// ---------------------------------------------------------------------------
extern "C" void kernel_launch(void* const* d_in, const int* in_sizes, int n_in,
                              void* d_out, int out_size, void* d_ws, size_t ws_size,
                              hipStream_t stream) {
    const float* x    = (const float*)d_in[0];
    const float* kv   = (const float*)d_in[1];
    const float* bias = (const float*)d_in[2];
    const int*   idx  = (const int*)d_in[3];
    float*       out  = (float*)d_out;

    const size_t xt_bytes = (size_t)INPUT_DIM * BATCH * sizeof(float); // 3.84 MB
    float* xt   = (float*)d_ws;

    // pick largest chunk count whose partial buffer fits the workspace
    int nchunk = 1;
    const int cand[] = {64, 32, 16, 8, 4, 2, 1};
    for (int i = 0; i < 7; ++i) {
        size_t need = xt_bytes + (size_t)cand[i] * 4 * (UNITS * 8) * sizeof(float);
        if (need <= ws_size) { nchunk = cand[i]; break; }
    }
    float* part = (float*)((char*)d_ws + xt_bytes);

    transpose_k<<<(INPUT_DIM * BATCH) / 256, 256, 0, stream>>>(x, xt);
    scatter_k<<<dim3(nchunk, 4), 1024, 0, stream>>>(idx, kv, xt, part, nchunk);
    reduce_k<<<(BATCH * UNITS) / 256, 256, 0, stream>>>(part, bias, out, nchunk);
}

// Round 2
// 168.877 us; speedup vs baseline: 1.0542x; 1.0542x over previous
//
#include <hip/hip_runtime.h>
#include <hip/hip_bf16.h>
#include <math.h>

// Problem constants (from reference)
#define INPUT_DIM 30000
#define UNITS     2048
#define NNZ       500000
#define BATCH     32

// ---------------------------------------------------------------------------
// Kernel 1: transpose x [32][30000] -> xt [30000][32]
// ---------------------------------------------------------------------------
__global__ __launch_bounds__(256) void transpose_k(const float* __restrict__ x,
                                                   float* __restrict__ xt) {
    int tid = blockIdx.x * 256 + threadIdx.x;     // 0 .. 960000-1
    int i = tid >> 5;                             // input-dim index
    int b = tid & 31;                             // batch index
    xt[tid] = x[b * INPUT_DIM + i];
}

// ---------------------------------------------------------------------------
// Kernel 2: scatter-accumulate.
// grid = (nchunk, 4): blockIdx.x = nnz chunk, blockIdx.y = batch group (8 rows).
// LDS acc covers ALL 2048 columns x 8 batch rows = 64 KB -> no filtering, no
// divergence, no global atomics. Each entry handled by 8 lanes (one per batch
// row). nchunk=128 -> 512 WGs -> 2 WGs/CU (128 KB LDS) = 32 waves/CU = 100%
// occupancy. Entry loop unrolled x2 for independent gather chains (MLP).
// ---------------------------------------------------------------------------
__global__ __launch_bounds__(1024) void scatter_k(const int* __restrict__ idx,
                                                  const float* __restrict__ kv,
                                                  const float* __restrict__ xt,
                                                  float* __restrict__ part,
                                                  int nchunk) {
    __shared__ float acc[UNITS * 8];              // 64 KB

    const int chunk = blockIdx.x;
    const int bg    = blockIdx.y;                 // batch group 0..3

    // vectorized LDS zero-init (4 x ds_write_b128 per thread)
    {
        float4* a4 = (float4*)acc;
        #pragma unroll
        for (int t = threadIdx.x; t < UNITS * 2; t += 1024)
            a4[t] = make_float4(0.f, 0.f, 0.f, 0.f);
    }
    __syncthreads();

    // int64 vs int32 index detection (uniform across grid):
    // int64 little-endian -> high words of col0,row1,col1 are all zero.
    const bool is64 = ((idx[3] | idx[5] | idx[7]) == 0);

    const int e0 = (int)((long long)NNZ * chunk / nchunk);
    const int e1 = (int)((long long)NNZ * (chunk + 1) / nchunk);

    const int bl = threadIdx.x & 7;               // batch-local 0..7
    const int b  = bg * 8 + bl;                   // global batch row
    const int eo = threadIdx.x >> 3;              // entry slot 0..127

    if (is64) {
        const int4* __restrict__ p = (const int4*)idx;   // {row_lo,row_hi,col_lo,col_hi}
        int e = e0 + eo;
        for (; e + 128 < e1; e += 256) {
            int4  qa = p[e];
            int4  qb = p[e + 128];
            float va = kv[e];
            float vb = kv[e + 128];
            float xa = xt[qa.x * 32 + b];
            float xb = xt[qb.x * 32 + b];
            atomicAdd(&acc[qa.z * 8 + bl], va * xa);
            atomicAdd(&acc[qb.z * 8 + bl], vb * xb);
        }
        if (e < e1) {
            int4  q = p[e];
            float v = kv[e];
            atomicAdd(&acc[q.z * 8 + bl], v * xt[q.x * 32 + b]);
        }
    } else {
        const int2* __restrict__ p = (const int2*)idx;   // {row, col}
        int e = e0 + eo;
        for (; e + 128 < e1; e += 256) {
            int2  qa = p[e];
            int2  qb = p[e + 128];
            float va = kv[e];
            float vb = kv[e + 128];
            float xa = xt[qa.x * 32 + b];
            float xb = xt[qb.x * 32 + b];
            atomicAdd(&acc[qa.y * 8 + bl], va * xa);
            atomicAdd(&acc[qb.y * 8 + bl], vb * xb);
        }
        if (e < e1) {
            int2  q = p[e];
            float v = kv[e];
            atomicAdd(&acc[q.y * 8 + bl], v * xt[q.x * 32 + b]);
        }
    }
    __syncthreads();

    // vectorized slab writeout (exclusive -> plain coalesced float4 stores)
    float4* __restrict__ dst = (float4*)(part + (size_t)(bg * nchunk + chunk) * (UNITS * 8));
    const float4* __restrict__ src = (const float4*)acc;
    #pragma unroll
    for (int t = threadIdx.x; t < UNITS * 2; t += 1024) dst[t] = src[t];
}

// ---------------------------------------------------------------------------
// Kernel 3: reduce partials over chunks (fully coalesced float4), add bias,
// tanh, write out [32][2048]. grid = (16, 4) x 256 threads.
// Slab element f = c*8+bl ; a float4 spans one c, bl..bl+3 (bl in {0,4}).
// ---------------------------------------------------------------------------
__global__ __launch_bounds__(256) void reduce_k(const float* __restrict__ part,
                                                const float* __restrict__ bias,
                                                float* __restrict__ out,
                                                int nchunk) {
    const int bg  = blockIdx.y;
    const int v   = blockIdx.x * 256 + threadIdx.x;   // float4 slot 0..4095
    const int f   = v * 4;                            // slab element index
    const int bl  = f & 7;                            // 0 or 4
    const int c   = f >> 3;

    const float4* __restrict__ p =
        (const float4*)(part + (size_t)bg * nchunk * (UNITS * 8)) + v;
    float4 s = make_float4(0.f, 0.f, 0.f, 0.f);
    #pragma unroll 4
    for (int k = 0; k < nchunk; ++k) {
        float4 q = p[(size_t)k * (UNITS * 2)];
        s.x += q.x; s.y += q.y; s.z += q.z; s.w += q.w;
    }
    const float bs = bias[c];
    const int   b0 = bg * 8 + bl;
    out[(b0 + 0) * UNITS + c] = tanhf(s.x + bs);
    out[(b0 + 1) * UNITS + c] = tanhf(s.y + bs);
    out[(b0 + 2) * UNITS + c] = tanhf(s.z + bs);
    out[(b0 + 3) * UNITS + c] = tanhf(s.w + bs);
}

// ---------------------------------------------------------------------------
extern "C" void kernel_launch(void* const* d_in, const int* in_sizes, int n_in,
                              void* d_out, int out_size, void* d_ws, size_t ws_size,
                              hipStream_t stream) {
    const float* x    = (const float*)d_in[0];
    const float* kv   = (const float*)d_in[1];
    const float* bias = (const float*)d_in[2];
    const int*   idx  = (const int*)d_in[3];
    float*       out  = (float*)d_out;

    const size_t xt_bytes = (size_t)INPUT_DIM * BATCH * sizeof(float); // 3.84 MB
    float* xt = (float*)d_ws;

    // largest chunk count whose partial buffer fits the workspace
    // (slab = 64 KB per (chunk, batch-group); 4 groups)
    int nchunk = 1;
    const int cand[] = {128, 112, 96, 80, 64, 48, 32, 16, 8, 4, 2, 1};
    for (int i = 0; i < 12; ++i) {
        size_t need = xt_bytes + (size_t)cand[i] * 4 * (UNITS * 8) * sizeof(float);
        if (need <= ws_size) { nchunk = cand[i]; break; }
    }
    float* part = (float*)((char*)d_ws + xt_bytes);

    transpose_k<<<(INPUT_DIM * BATCH) / 256, 256, 0, stream>>>(x, xt);
    scatter_k<<<dim3(nchunk, 4), 1024, 0, stream>>>(idx, kv, xt, part, nchunk);
    reduce_k<<<dim3(16, 4), 256, 0, stream>>>(part, bias, out, nchunk);
}